// Round 17
// baseline (206.298 us; speedup 1.0000x reference)
//
#include <hip/hip_runtime.h>
#include <math.h>

#define GCOUNT 512
#define HDIM 128
#define EPG 2048                 // edge slots per graph (fixed across layers)
#define E_TOTAL (GCOUNT * EPG)   // 1,048,576
#define DEADE 0xFFFFFFFFu

typedef __attribute__((ext_vector_type(8))) short short8;
typedef __attribute__((ext_vector_type(4))) float f32x4;

__device__ inline unsigned short f2bf(float f) {
  unsigned int u = __float_as_uint(f);
  return (unsigned short)((u + 0x7FFFu + ((u >> 16) & 1u)) >> 16);
}
__device__ inline float bf2f(unsigned short s) {
  return __uint_as_float(((unsigned int)s) << 16);
}
__device__ inline float4 z4() { return make_float4(0.f, 0.f, 0.f, 0.f); }
__device__ inline float4 ld4(const float* p) { return *(const float4*)p; }
__device__ inline void fma4(float4& u, float w, float4 x) {
  u.x = fmaf(w, x.x, u.x); u.y = fmaf(w, x.y, u.y);
  u.z = fmaf(w, x.z, u.z); u.w = fmaf(w, x.w, u.w);
}
__device__ inline float4 fin4(float4 u, float4 s, float4 b, float dv) {
  float4 r;
  r.x = fmaxf(fmaf(dv, fmaf(s.x, dv, u.x), b.x), 0.f);
  r.y = fmaxf(fmaf(dv, fmaf(s.y, dv, u.y), b.y), 0.f);
  r.z = fmaxf(fmaf(dv, fmaf(s.z, dv, u.z), b.z), 0.f);
  r.w = fmaxf(fmaf(dv, fmaf(s.w, dv, u.w), b.w), 0.f);
  return r;
}
__device__ inline float dot4(float4 a, float4 b) {
  return a.x * b.x + a.y * b.y + a.z * b.z + a.w * b.w;
}
__device__ inline float4 scale4(float4 v, float s) {
  v.x *= s; v.y *= s; v.z *= s; v.w *= s; return v;
}

// ---------------------------------------------------------------- W prepack x3 in one launch
// grid 24 blocks: blockIdx>>3 selects W, blockIdx&7 is the tile as before.
__global__ __launch_bounds__(256) void k_wsplit3(const float* __restrict__ W0,
                                                 const float* __restrict__ W1,
                                                 const float* __restrict__ W2,
                                                 unsigned short* __restrict__ outAll) {
  int b = blockIdx.x >> 3;
  const float* W = (b == 0) ? W0 : (b == 1 ? W1 : W2);
  unsigned short* out = outAll + b * 49152;           // 96 KB per W
  int t = (blockIdx.x & 7) * 256 + threadIdx.x;       // 0..2047
  int lane = t & 63;
  int ct = (t >> 6) & 7;
  int kc = t >> 9;
  int kbase = kc * 32 + (lane >> 4) * 8;
  int col = ct * 16 + (lane & 15);
#pragma unroll
  for (int j = 0; j < 8; j++) {
    float w = W[(size_t)(kbase + j) * HDIM + col];
    unsigned short h0 = f2bf(w);  float g0 = bf2f(h0);
    unsigned short h1 = f2bf(w - g0);
    int base = (kc * 8 + ct) * 512 + lane * 8 + j;
    out[base]         = h0;
    out[base + 16384] = h1;
  }
}

// ---------------------------------------------------------------- whole network, one block per graph
__global__ __launch_bounds__(1024, 1) void k_net(
    const float* __restrict__ xIn, const int* __restrict__ ei0,
    const unsigned short* __restrict__ Ws0,
    const unsigned short* __restrict__ Ws1,
    const unsigned short* __restrict__ Ws2,
    const float* __restrict__ b0, const float* __restrict__ p0,
    const float* __restrict__ b1, const float* __restrict__ p1,
    const float* __restrict__ b2, const float* __restrict__ p2,
    const float* __restrict__ Wg, const float* __restrict__ bgp,
    float* __restrict__ outp) {

  __shared__ __align__(16) float h_s[256 * 132];   // 135168 B
  __shared__ unsigned int es[EPG];                 // 8 KB  (src | dst<<16), DEADE = dead
  __shared__ unsigned short ss[EPG];               // 4 KB  CSR-sorted local src ids
  __shared__ __align__(16) int deg[256];           // next layer's degree (built in P8)
  __shared__ int cnt[256];                         // nmap
  __shared__ int ofs[256];                         // scatter offsets; sort idx ping-pong
  __shared__ int rp[260];
  __shared__ float dinv_s[256];
  __shared__ float rawsc_s[256];
  __shared__ float hd[256];                        // h' . Wg per row
  __shared__ float sc[256];                        // sort keys ping-pong -> att weights
  __shared__ int   idx[256];
  __shared__ float tn[256];
  __shared__ float accout[128];
  __shared__ float part[512];                      // bias/p/Wg stage; sort ping-pong; P11 partials
  __shared__ float red[8];
  __shared__ float snorm_s;

  int g = blockIdx.x, t = threadIdx.x;
  int lane = t & 63, wv = t >> 6;
  int eb = g * EPG;
  float bgv = bgp[0];

  // ========== P0: zero deg/accout, stage x, edges -> es + layer-0 histogram
  if (t < 256) deg[t] = 0;
  if (t < 128) accout[t] = 0.f;
  __syncthreads();
  {
    const float4* xg = (const float4*)(xIn + (size_t)g * 256 * HDIM);
    for (int i = t; i < 8192; i += 1024) {
      int r = i >> 5, q = i & 31;
      *(float4*)&h_s[r * 132 + (q << 2)] = xg[i];
    }
  }
#pragma unroll
  for (int q = 0; q < 2; q++) {
    int e = t + q * 1024;
    int s_ = ei0[eb + e] - g * 256;
    int d_ = ei0[E_TOTAL + eb + e] - g * 256;
    es[e] = (unsigned)s_ | ((unsigned)d_ << 16);
    atomicAdd(&deg[d_], 1);
  }
  __syncthreads();

  int n = 256;
#pragma unroll 1
  for (int layer = 0; layer < 3; layer++) {
    const unsigned short* Ws = (layer == 0) ? Ws0 : (layer == 1 ? Ws1 : Ws2);
    const float* bias = (layer == 0) ? b0 : (layer == 1 ? b1 : b2);
    const float* p    = (layer == 0) ? p0 : (layer == 1 ? p1 : p2);
    int k = (layer == 0) ? 205 : (layer == 1 ? 164 : 132);
    int T = (n + 15) >> 4;                      // 16-row tiles; all waves GEMM

    // ========== P1: GEMM, 4-term bf16 split (acc[8] = 32 AGPRs)
    if (wv < T) {
      int rbase = wv * 16;
      int arow = lane & 15, kgrp = (lane >> 4) * 8;
      f32x4 acc[8];
#pragma unroll
      for (int ct = 0; ct < 8; ct++) acc[ct] = (f32x4){0.f, 0.f, 0.f, 0.f};
#pragma unroll
      for (int kc = 0; kc < 4; kc++) {
        short8 fa0, fa1;
        {
          const float* ap = &h_s[(rbase + arow) * 132 + kc * 32 + kgrp];
          float4 x0 = ld4(ap);
          float4 x1 = ld4(ap + 4);
          float v[8] = {x0.x, x0.y, x0.z, x0.w, x1.x, x1.y, x1.z, x1.w};
#pragma unroll
          for (int j = 0; j < 8; j++) {
            float a = v[j];
            unsigned short q0 = f2bf(a);
            unsigned short q1 = f2bf(a - bf2f(q0));
            fa0[j] = (short)q0; fa1[j] = (short)q1;
          }
        }
#pragma unroll
        for (int ct = 0; ct < 8; ct++) {
          const unsigned short* wb = Ws + (kc * 8 + ct) * 512 + lane * 8;
          short8 w0 = *(const short8*)wb;
          short8 w1 = *(const short8*)(wb + 16384);
          acc[ct] = __builtin_amdgcn_mfma_f32_16x16x32_bf16(fa0, w0, acc[ct], 0, 0, 0);
          acc[ct] = __builtin_amdgcn_mfma_f32_16x16x32_bf16(fa0, w1, acc[ct], 0, 0, 0);
          acc[ct] = __builtin_amdgcn_mfma_f32_16x16x32_bf16(fa1, w0, acc[ct], 0, 0, 0);
          acc[ct] = __builtin_amdgcn_mfma_f32_16x16x32_bf16(fa1, w1, acc[ct], 0, 0, 0);
        }
      }
      int crow = (lane >> 4) * 4, ccol = lane & 15;
#pragma unroll
      for (int ct = 0; ct < 8; ct++)
#pragma unroll
        for (int reg = 0; reg < 4; reg++)
          h_s[(rbase + crow + reg) * 132 + ct * 16 + ccol] = acc[ct][reg];
    }
    __syncthreads();

    // ========== P2: dinv + scan (wave0) + snorm (wave1) + stage bias/p/Wg
    if (t < 256) dinv_s[t] = rsqrtf((float)deg[t] + 1.0f);
    if (wv == 0) {
      int4 c4 = *(const int4*)&deg[lane << 2];
      int s4 = c4.x + c4.y + c4.z + c4.w;
      int run = s4;
#pragma unroll
      for (int o = 1; o < 64; o <<= 1) {
        int v = __shfl_up(run, o);
        if (lane >= o) run += v;
      }
      int base = run - s4;
      int v1 = base + c4.x, v2 = v1 + c4.y, v3 = v2 + c4.z;
      int li = lane << 2;
      rp[li] = base; rp[li + 1] = v1; rp[li + 2] = v2; rp[li + 3] = v3;
      ofs[li] = base; ofs[li + 1] = v1; ofs[li + 2] = v2; ofs[li + 3] = v3;
      if (lane == 63) rp[256] = run;
    }
    if (wv == 1) {
      float q = p[lane] * p[lane] + p[lane + 64] * p[lane + 64];
#pragma unroll
      for (int o = 32; o > 0; o >>= 1) q += __shfl_xor(q, o);
      if (lane == 0) snorm_s = sqrtf(q);
    }
    if (t >= 128 && t < 512) {
      int i = t - 128;
      part[i] = (i < 128) ? bias[i] : (i < 256 ? p[i - 128] : Wg[i - 256]);
    }
    __syncthreads();

    // ========== P3: scatter CSR + preset nmap + zero deg for next layer
    if (t < 256) { cnt[t] = -1; deg[t] = 0; }
    for (int e = t; e < EPG; e += 1024) {
      unsigned u = es[e];
      if (u != DEADE) {
        int pos = atomicAdd(&ofs[u >> 16], 1);
        ss[pos] = (unsigned short)(u & 0xFFFFu);
      }
    }
    __syncthreads();

    // ========== P4: aggregate, 2 passes x 2 column-groups, 1-edge scalar lookahead
    {
      int dstT = t >> 2;
      int cq = (t & 3) << 3;                    // 0,8,16,24
      bool dok = dstT < n;
      int begT = 0, endT = 0; float dvT = 0.f;
      if (dok) { begT = rp[dstT]; endT = rp[dstT + 1]; dvT = dinv_s[dstT]; }
      float sp = 0.f, sg = 0.f;
      float4 rA0, rA1, rB0, rB1;
      // ---- pass 1: columns [0,64)
      if (dok) {
        float4 uA0 = z4(), uA1 = z4(), uB0 = z4(), uB1 = z4();
        int j = begT;
        int sa = (j < endT) ? ss[j] : 0;
        float wa = (j < endT) ? dinv_s[sa] : 0.f;
        for (; j < endT; ) {
          int jn = j + 1;
          int sa2 = (jn < endT) ? ss[jn] : 0;            // prefetch next edge's scalars
          float wa2 = (jn < endT) ? dinv_s[sa2] : 0.f;
          const float* ha = &h_s[sa * 132 + cq];
          fma4(uA0, wa, ld4(ha));      fma4(uA1, wa, ld4(ha + 4));
          fma4(uB0, wa, ld4(ha + 32)); fma4(uB1, wa, ld4(ha + 36));
          sa = sa2; wa = wa2; j = jn;
        }
        const float* hdp = &h_s[dstT * 132 + cq];
        rA0 = fin4(uA0, ld4(hdp),      ld4(&part[cq]),      dvT);
        rA1 = fin4(uA1, ld4(hdp + 4),  ld4(&part[cq + 4]),  dvT);
        rB0 = fin4(uB0, ld4(hdp + 32), ld4(&part[32 + cq]), dvT);
        rB1 = fin4(uB1, ld4(hdp + 36), ld4(&part[32 + cq + 4]), dvT);
        sp += dot4(rA0, ld4(&part[128 + cq])) + dot4(rA1, ld4(&part[128 + cq + 4]))
            + dot4(rB0, ld4(&part[160 + cq])) + dot4(rB1, ld4(&part[160 + cq + 4]));
        sg += dot4(rA0, ld4(&part[256 + cq])) + dot4(rA1, ld4(&part[256 + cq + 4]))
            + dot4(rB0, ld4(&part[288 + cq])) + dot4(rB1, ld4(&part[288 + cq + 4]));
      }
      __syncthreads();
      if (dok) {
        float* hw = &h_s[dstT * 132 + cq];
        *(float4*)hw = rA0; *(float4*)(hw + 4) = rA1;
        *(float4*)(hw + 32) = rB0; *(float4*)(hw + 36) = rB1;
      }
      // ---- pass 2: columns [64,128)  (reads disjoint from pass-1 writes)
      if (dok) {
        float4 uA0 = z4(), uA1 = z4(), uB0 = z4(), uB1 = z4();
        int j = begT;
        int sa = (j < endT) ? ss[j] : 0;
        float wa = (j < endT) ? dinv_s[sa] : 0.f;
        for (; j < endT; ) {
          int jn = j + 1;
          int sa2 = (jn < endT) ? ss[jn] : 0;
          float wa2 = (jn < endT) ? dinv_s[sa2] : 0.f;
          const float* ha = &h_s[sa * 132 + 64 + cq];
          fma4(uA0, wa, ld4(ha));      fma4(uA1, wa, ld4(ha + 4));
          fma4(uB0, wa, ld4(ha + 32)); fma4(uB1, wa, ld4(ha + 36));
          sa = sa2; wa = wa2; j = jn;
        }
        const float* hdp = &h_s[dstT * 132 + 64 + cq];
        rA0 = fin4(uA0, ld4(hdp),      ld4(&part[64 + cq]),  dvT);
        rA1 = fin4(uA1, ld4(hdp + 4),  ld4(&part[64 + cq + 4]), dvT);
        rB0 = fin4(uB0, ld4(hdp + 32), ld4(&part[96 + cq]),  dvT);
        rB1 = fin4(uB1, ld4(hdp + 36), ld4(&part[96 + cq + 4]), dvT);
        sp += dot4(rA0, ld4(&part[192 + cq])) + dot4(rA1, ld4(&part[192 + cq + 4]))
            + dot4(rB0, ld4(&part[224 + cq])) + dot4(rB1, ld4(&part[224 + cq + 4]));
        sg += dot4(rA0, ld4(&part[320 + cq])) + dot4(rA1, ld4(&part[320 + cq + 4]))
            + dot4(rB0, ld4(&part[352 + cq])) + dot4(rB1, ld4(&part[352 + cq + 4]));
      }
      __syncthreads();
      if (dok) {
        float* hw = &h_s[dstT * 132 + 64 + cq];
        *(float4*)hw = rA0; *(float4*)(hw + 4) = rA1;
        *(float4*)(hw + 32) = rB0; *(float4*)(hw + 36) = rB1;
      }
      sp += __shfl_xor(sp, 1); sp += __shfl_xor(sp, 2);
      sg += __shfl_xor(sg, 1); sg += __shfl_xor(sg, 2);
      if (dok && (t & 3) == 0) { rawsc_s[dstT] = sp; hd[dstT] = sg; }
    }
    __syncthreads();

    // ========== P6: bitonic sort (raw dot desc, idx asc); LDS stages ping-pong
    float key = -INFINITY;
    int id = t & 255;
    if (t < n) key = rawsc_s[t];
    {
      int pp = 0;
      for (int size = 2; size <= 256; size <<= 1) {
        for (int stride = size >> 1; stride > 0; stride >>= 1) {
          if (stride > 32) {
            float* sb = pp ? (float*)part : sc;
            int* ib = pp ? ofs : idx;
            if (t < 256) { sb[t] = key; ib[t] = id; }
            __syncthreads();
            if (t < 256) {
              float pk = sb[t ^ stride];
              int pi = ib[t ^ stride];
              bool want = ((t & size) == 0);
              bool lowr = ((t & stride) == 0);
              bool mineFirst = (key > pk) || (key == pk && id < pi);
              if (mineFirst != (want == lowr)) { key = pk; id = pi; }
            }
            pp ^= 1;
          } else {
            if (t < 256) {
              float pk = __shfl_xor(key, stride);
              int pi = __shfl_xor(id, stride);
              bool want = ((t & size) == 0);
              bool lowr = ((t & stride) == 0);
              bool mineFirst = (key > pk) || (key == pk && id < pi);
              if (mineFirst != (want == lowr)) { key = pk; id = pi; }
            }
          }
        }
      }
    }
    __syncthreads();
    if (t < 256) idx[t] = id;
    __syncthreads();

    // ========== P7: tn, nmap, gates + per-wave max
    float gate = -INFINITY;
    if (t < k) {
      float tnv = tanhf(key / snorm_s);
      tn[t] = tnv;
      cnt[id] = t;
      gate = fmaf(hd[id], tnv, bgv);
    }
    if (wv < 4) {
      float m = gate;
#pragma unroll
      for (int o = 32; o > 0; o >>= 1) m = fmaxf(m, __shfl_xor(m, o));
      if (lane == 0) red[wv] = m;
    }
    __syncthreads();

    // ========== P8: softmax exp+sum (waves 0-3) || remap + next-layer histogram (waves 8-15)
    float ex = 0.f;
    if (wv < 4) {
      float m = fmaxf(fmaxf(red[0], red[1]), fmaxf(red[2], red[3]));
      ex = (t < k) ? __expf(gate - m) : 0.f;
      float s = ex;
#pragma unroll
      for (int o = 32; o > 0; o >>= 1) s += __shfl_xor(s, o);
      if (lane == 0) red[4 + wv] = s;
    } else if (wv >= 8 && layer < 2) {
      int tt = t - 512;
#pragma unroll
      for (int q = 0; q < 4; q++) {
        int e = tt + q * 512;
        unsigned u = es[e];
        unsigned o = DEADE;
        if (u != DEADE) {
          int ns = cnt[u & 0xFFFFu], nd = cnt[u >> 16];
          if (ns >= 0 && nd >= 0) o = (unsigned)ns | ((unsigned)nd << 16);
        }
        es[e] = o;
        if (o != DEADE) atomicAdd(&deg[o >> 16], 1);
      }
    }
    __syncthreads();

    // ========== P9: att weights
    if (t < 256) {
      float inv = 1.f / (red[4] + red[5] + red[6] + red[7]);
      float a = (t < k) ? ex * inv : 0.f;
      sc[t] = (layer == 2) ? a * tn[t] : a;
    }
    __syncthreads();

    if (layer < 2) {
      // ========== P10: in-LDS compaction, single pass (all reads before any write)
      {
        int rT = t >> 2;
        int cq4 = (t & 3) << 3;
        bool rok = rT < k;
        int src = 0; float tr = 0.f;
        if (rok) { src = idx[rT]; tr = tn[rT]; }
        float4 vA0, vA1, vB0, vB1, vC0, vC1, vD0, vD1;
        if (rok) {
          const float* hp = &h_s[src * 132 + cq4];
          vA0 = scale4(ld4(hp), tr);       vA1 = scale4(ld4(hp + 4), tr);
          vB0 = scale4(ld4(hp + 32), tr);  vB1 = scale4(ld4(hp + 36), tr);
          vC0 = scale4(ld4(hp + 64), tr);  vC1 = scale4(ld4(hp + 68), tr);
          vD0 = scale4(ld4(hp + 96), tr);  vD1 = scale4(ld4(hp + 100), tr);
        }
        __syncthreads();
        if (rok) {
          float* hw = &h_s[rT * 132 + cq4];
          *(float4*)hw = vA0;        *(float4*)(hw + 4) = vA1;
          *(float4*)(hw + 32) = vB0; *(float4*)(hw + 36) = vB1;
          *(float4*)(hw + 64) = vC0; *(float4*)(hw + 68) = vC1;
          *(float4*)(hw + 96) = vD0; *(float4*)(hw + 100) = vD1;
        }
      }
      __syncthreads();
      // ========== P11: attention partial sums over compacted rows
      if (t < 512) {
        int grp = t >> 7, c2 = t & 127;
        float pp2 = 0.f;
        for (int r = grp; r < k; r += 4) pp2 = fmaf(sc[r], h_s[r * 132 + c2], pp2);
        part[t] = pp2;
      }
      __syncthreads();
      if (t < 128) accout[t] += part[t] + part[128 + t] + part[256 + t] + part[384 + t];
      __syncthreads();
    } else {
      // ========== final attention (via idx, tn folded into sc) + output write
      if (t < 512) {
        int grp = t >> 7, c2 = t & 127;
        float pp2 = 0.f;
        for (int r = grp; r < k; r += 4) pp2 = fmaf(sc[r], h_s[idx[r] * 132 + c2], pp2);
        part[t] = pp2;
      }
      __syncthreads();
      if (t < 128)
        outp[(size_t)g * HDIM + t] =
            accout[t] + part[t] + part[128 + t] + part[256 + t] + part[384 + t];
    }
    n = k;
  }
}

// ================================================================ launch
extern "C" void kernel_launch(void* const* d_in, const int* in_sizes, int n_in,
                              void* d_out, int out_size, void* d_ws, size_t ws_size,
                              hipStream_t stream) {
  const float* x  = (const float*)d_in[0];
  const int*   ei = (const int*)d_in[1];
  const float* W0 = (const float*)d_in[2];
  const float* b0 = (const float*)d_in[3];
  const float* p0 = (const float*)d_in[4];
  const float* W1 = (const float*)d_in[5];
  const float* b1 = (const float*)d_in[6];
  const float* p1 = (const float*)d_in[7];
  const float* W2 = (const float*)d_in[8];
  const float* b2 = (const float*)d_in[9];
  const float* p2 = (const float*)d_in[10];
  const float* Wg = (const float*)d_in[11];
  const float* bg = (const float*)d_in[12];
  float* out = (float*)d_out;

  unsigned char* ws = (unsigned char*)d_ws;
  unsigned short* WspA = (unsigned short*)(ws);        // 3 x 96 KB
  unsigned short* Wsp0 = WspA;
  unsigned short* Wsp1 = (unsigned short*)(ws + 98304ull);
  unsigned short* Wsp2 = (unsigned short*)(ws + 196608ull);

  k_wsplit3<<<24, 256, 0, stream>>>(W0, W1, W2, WspA);
  k_net<<<GCOUNT, 1024, 0, stream>>>(x, ei, Wsp0, Wsp1, Wsp2,
                                     b0, p0, b1, p1, b2, p2, Wg, bg, out);
}

// Round 18
// 200.088 us; speedup vs baseline: 1.0310x; 1.0310x over previous
//
#include <hip/hip_runtime.h>
#include <math.h>

#define GCOUNT 512
#define HDIM 128
#define EPG 2048                 // edge slots per graph (fixed across layers)
#define E_TOTAL (GCOUNT * EPG)   // 1,048,576
#define DEADE 0xFFFFFFFFu

typedef __attribute__((ext_vector_type(8))) short short8;
typedef __attribute__((ext_vector_type(4))) float f32x4;

__device__ inline unsigned short f2bf(float f) {
  unsigned int u = __float_as_uint(f);
  return (unsigned short)((u + 0x7FFFu + ((u >> 16) & 1u)) >> 16);
}
__device__ inline float bf2f(unsigned short s) {
  return __uint_as_float(((unsigned int)s) << 16);
}
__device__ inline float4 z4() { return make_float4(0.f, 0.f, 0.f, 0.f); }
__device__ inline float4 ld4(const float* p) { return *(const float4*)p; }
__device__ inline void fma4(float4& u, float w, float4 x) {
  u.x = fmaf(w, x.x, u.x); u.y = fmaf(w, x.y, u.y);
  u.z = fmaf(w, x.z, u.z); u.w = fmaf(w, x.w, u.w);
}
__device__ inline float4 fin4(float4 u, float4 s, float4 b, float dv) {
  float4 r;
  r.x = fmaxf(fmaf(dv, fmaf(s.x, dv, u.x), b.x), 0.f);
  r.y = fmaxf(fmaf(dv, fmaf(s.y, dv, u.y), b.y), 0.f);
  r.z = fmaxf(fmaf(dv, fmaf(s.z, dv, u.z), b.z), 0.f);
  r.w = fmaxf(fmaf(dv, fmaf(s.w, dv, u.w), b.w), 0.f);
  return r;
}
__device__ inline float dot4(float4 a, float4 b) {
  return a.x * b.x + a.y * b.y + a.z * b.z + a.w * b.w;
}
__device__ inline float4 scale4(float4 v, float s) {
  v.x *= s; v.y *= s; v.z *= s; v.w *= s; return v;
}

// ---------------------------------------------------------------- W prepack: bf16 split, MFMA-B-fragment layout
__global__ __launch_bounds__(256) void k_wsplit(const float* __restrict__ W,
                                                unsigned short* __restrict__ out) {
  int t = blockIdx.x * 256 + threadIdx.x;   // 2048 = (kc*8+ct)*64+lane
  int lane = t & 63;
  int ct = (t >> 6) & 7;
  int kc = t >> 9;
  int kbase = kc * 32 + (lane >> 4) * 8;
  int col = ct * 16 + (lane & 15);
#pragma unroll
  for (int j = 0; j < 8; j++) {
    float w = W[(size_t)(kbase + j) * HDIM + col];
    unsigned short h0 = f2bf(w);  float g0 = bf2f(h0);
    unsigned short h1 = f2bf(w - g0);
    int base = (kc * 8 + ct) * 512 + lane * 8 + j;
    out[base]         = h0;
    out[base + 16384] = h1;
  }
}

// ---------------------------------------------------------------- whole network, one block per graph
__global__ __launch_bounds__(1024, 1) void k_net(
    const float* __restrict__ xIn, const int* __restrict__ ei0,
    const unsigned short* __restrict__ Ws0,
    const unsigned short* __restrict__ Ws1,
    const unsigned short* __restrict__ Ws2,
    const float* __restrict__ b0, const float* __restrict__ p0,
    const float* __restrict__ b1, const float* __restrict__ p1,
    const float* __restrict__ b2, const float* __restrict__ p2,
    const float* __restrict__ Wg, const float* __restrict__ bgp,
    float* __restrict__ outp) {

  __shared__ __align__(16) float h_s[256 * 132];   // 135168 B
  __shared__ unsigned int es[EPG];                 // 8 KB  (src | dst<<16), DEADE = dead
  __shared__ unsigned short ss[EPG];               // 4 KB  CSR-sorted local src ids
  __shared__ __align__(16) int deg[256];           // next layer's degree (built in P8)
  __shared__ int cnt[256];                         // nmap
  __shared__ int ofs[256];                         // scatter offsets; sort idx ping-pong
  __shared__ int rp[260];
  __shared__ float dinv_s[256];
  __shared__ float rawsc_s[256];
  __shared__ float hd[256];                        // h' . Wg per row
  __shared__ float sc[256];                        // sort keys ping-pong -> att weights
  __shared__ int   idx[256];
  __shared__ float tn[256];
  __shared__ float accout[128];
  __shared__ float part[512];                      // P2-P4: bias/p/Wg stage; sort ping-pong; P11 partials
  __shared__ float red[8];
  __shared__ float snorm_s;

  int g = blockIdx.x, t = threadIdx.x;
  int lane = t & 63, wv = t >> 6;
  int eb = g * EPG;
  float bgv = bgp[0];

  // ========== P0: zero deg/accout, stage x, edges -> es + layer-0 histogram
  if (t < 256) deg[t] = 0;
  if (t < 128) accout[t] = 0.f;
  __syncthreads();
  {
    const float4* xg = (const float4*)(xIn + (size_t)g * 256 * HDIM);
    for (int i = t; i < 8192; i += 1024) {
      int r = i >> 5, q = i & 31;
      *(float4*)&h_s[r * 132 + (q << 2)] = xg[i];
    }
  }
#pragma unroll
  for (int q = 0; q < 2; q++) {
    int e = t + q * 1024;
    int s_ = ei0[eb + e] - g * 256;
    int d_ = ei0[E_TOTAL + eb + e] - g * 256;
    es[e] = (unsigned)s_ | ((unsigned)d_ << 16);
    atomicAdd(&deg[d_], 1);
  }
  __syncthreads();

  int n = 256;
#pragma unroll 1
  for (int layer = 0; layer < 3; layer++) {
    const unsigned short* Ws = (layer == 0) ? Ws0 : (layer == 1 ? Ws1 : Ws2);
    const float* bias = (layer == 0) ? b0 : (layer == 1 ? b1 : b2);
    const float* p    = (layer == 0) ? p0 : (layer == 1 ? p1 : p2);
    int k = (layer == 0) ? 205 : (layer == 1 ? 164 : 132);
    int T = (n + 15) >> 4;                      // 16-row tiles; all waves GEMM

    // ========== P1: GEMM, 4-term bf16 split (acc[8] = 32 AGPRs)
    if (wv < T) {
      int rbase = wv * 16;
      int arow = lane & 15, kgrp = (lane >> 4) * 8;
      f32x4 acc[8];
#pragma unroll
      for (int ct = 0; ct < 8; ct++) acc[ct] = (f32x4){0.f, 0.f, 0.f, 0.f};
#pragma unroll
      for (int kc = 0; kc < 4; kc++) {
        short8 fa0, fa1;
        {
          const float* ap = &h_s[(rbase + arow) * 132 + kc * 32 + kgrp];
          float4 x0 = ld4(ap);
          float4 x1 = ld4(ap + 4);
          float v[8] = {x0.x, x0.y, x0.z, x0.w, x1.x, x1.y, x1.z, x1.w};
#pragma unroll
          for (int j = 0; j < 8; j++) {
            float a = v[j];
            unsigned short q0 = f2bf(a);
            unsigned short q1 = f2bf(a - bf2f(q0));
            fa0[j] = (short)q0; fa1[j] = (short)q1;
          }
        }
#pragma unroll
        for (int ct = 0; ct < 8; ct++) {
          const unsigned short* wb = Ws + (kc * 8 + ct) * 512 + lane * 8;
          short8 w0 = *(const short8*)wb;
          short8 w1 = *(const short8*)(wb + 16384);
          acc[ct] = __builtin_amdgcn_mfma_f32_16x16x32_bf16(fa0, w0, acc[ct], 0, 0, 0);
          acc[ct] = __builtin_amdgcn_mfma_f32_16x16x32_bf16(fa0, w1, acc[ct], 0, 0, 0);
          acc[ct] = __builtin_amdgcn_mfma_f32_16x16x32_bf16(fa1, w0, acc[ct], 0, 0, 0);
          acc[ct] = __builtin_amdgcn_mfma_f32_16x16x32_bf16(fa1, w1, acc[ct], 0, 0, 0);
        }
      }
      int crow = (lane >> 4) * 4, ccol = lane & 15;
#pragma unroll
      for (int ct = 0; ct < 8; ct++)
#pragma unroll
        for (int reg = 0; reg < 4; reg++)
          h_s[(rbase + crow + reg) * 132 + ct * 16 + ccol] = acc[ct][reg];
    }
    __syncthreads();

    // ========== P2: dinv + scan (wave0) + snorm (wave1) + stage bias/p/Wg
    if (t < 256) dinv_s[t] = rsqrtf((float)deg[t] + 1.0f);
    if (wv == 0) {
      int4 c4 = *(const int4*)&deg[lane << 2];
      int s4 = c4.x + c4.y + c4.z + c4.w;
      int run = s4;
#pragma unroll
      for (int o = 1; o < 64; o <<= 1) {
        int v = __shfl_up(run, o);
        if (lane >= o) run += v;
      }
      int base = run - s4;
      int v1 = base + c4.x, v2 = v1 + c4.y, v3 = v2 + c4.z;
      int li = lane << 2;
      rp[li] = base; rp[li + 1] = v1; rp[li + 2] = v2; rp[li + 3] = v3;
      ofs[li] = base; ofs[li + 1] = v1; ofs[li + 2] = v2; ofs[li + 3] = v3;
      if (lane == 63) rp[256] = run;
    }
    if (wv == 1) {
      float q = p[lane] * p[lane] + p[lane + 64] * p[lane + 64];
#pragma unroll
      for (int o = 32; o > 0; o >>= 1) q += __shfl_xor(q, o);
      if (lane == 0) snorm_s = sqrtf(q);
    }
    if (t >= 128 && t < 512) {
      int i = t - 128;
      part[i] = (i < 128) ? bias[i] : (i < 256 ? p[i - 128] : Wg[i - 256]);
    }
    __syncthreads();

    // ========== P3: scatter CSR + preset nmap + zero deg for next layer
    if (t < 256) { cnt[t] = -1; deg[t] = 0; }
    for (int e = t; e < EPG; e += 1024) {
      unsigned u = es[e];
      if (u != DEADE) {
        int pos = atomicAdd(&ofs[u >> 16], 1);
        ss[pos] = (unsigned short)(u & 0xFFFFu);
      }
    }
    __syncthreads();

    // ========== P4: aggregate, 2 passes x 2 column-groups (ss/dinv looked up 2x not 4x)
    {
      int dstT = t >> 2;
      int cq = (t & 3) << 3;                    // 0,8,16,24
      bool dok = dstT < n;
      int begT = 0, endT = 0; float dvT = 0.f;
      if (dok) { begT = rp[dstT]; endT = rp[dstT + 1]; dvT = dinv_s[dstT]; }
      float sp = 0.f, sg = 0.f;
      float4 rA0, rA1, rB0, rB1;
      // ---- pass 1: columns [0,64)
      if (dok) {
        float4 uA0 = z4(), uA1 = z4(), uB0 = z4(), uB1 = z4();
        for (int j = begT; j < endT; ++j) {
          int sa = ss[j];
          float wa = dinv_s[sa];
          const float* ha = &h_s[sa * 132 + cq];
          fma4(uA0, wa, ld4(ha));      fma4(uA1, wa, ld4(ha + 4));
          fma4(uB0, wa, ld4(ha + 32)); fma4(uB1, wa, ld4(ha + 36));
        }
        const float* hdp = &h_s[dstT * 132 + cq];
        rA0 = fin4(uA0, ld4(hdp),      ld4(&part[cq]),      dvT);
        rA1 = fin4(uA1, ld4(hdp + 4),  ld4(&part[cq + 4]),  dvT);
        rB0 = fin4(uB0, ld4(hdp + 32), ld4(&part[32 + cq]), dvT);
        rB1 = fin4(uB1, ld4(hdp + 36), ld4(&part[32 + cq + 4]), dvT);
        sp += dot4(rA0, ld4(&part[128 + cq])) + dot4(rA1, ld4(&part[128 + cq + 4]))
            + dot4(rB0, ld4(&part[160 + cq])) + dot4(rB1, ld4(&part[160 + cq + 4]));
        sg += dot4(rA0, ld4(&part[256 + cq])) + dot4(rA1, ld4(&part[256 + cq + 4]))
            + dot4(rB0, ld4(&part[288 + cq])) + dot4(rB1, ld4(&part[288 + cq + 4]));
      }
      __syncthreads();
      if (dok) {
        float* hw = &h_s[dstT * 132 + cq];
        *(float4*)hw = rA0; *(float4*)(hw + 4) = rA1;
        *(float4*)(hw + 32) = rB0; *(float4*)(hw + 36) = rB1;
      }
      // ---- pass 2: columns [64,128)  (reads disjoint from pass-1 writes)
      if (dok) {
        float4 uA0 = z4(), uA1 = z4(), uB0 = z4(), uB1 = z4();
        for (int j = begT; j < endT; ++j) {
          int sa = ss[j];
          float wa = dinv_s[sa];
          const float* ha = &h_s[sa * 132 + 64 + cq];
          fma4(uA0, wa, ld4(ha));      fma4(uA1, wa, ld4(ha + 4));
          fma4(uB0, wa, ld4(ha + 32)); fma4(uB1, wa, ld4(ha + 36));
        }
        const float* hdp = &h_s[dstT * 132 + 64 + cq];
        rA0 = fin4(uA0, ld4(hdp),      ld4(&part[64 + cq]),  dvT);
        rA1 = fin4(uA1, ld4(hdp + 4),  ld4(&part[64 + cq + 4]), dvT);
        rB0 = fin4(uB0, ld4(hdp + 32), ld4(&part[96 + cq]),  dvT);
        rB1 = fin4(uB1, ld4(hdp + 36), ld4(&part[96 + cq + 4]), dvT);
        sp += dot4(rA0, ld4(&part[192 + cq])) + dot4(rA1, ld4(&part[192 + cq + 4]))
            + dot4(rB0, ld4(&part[224 + cq])) + dot4(rB1, ld4(&part[224 + cq + 4]));
        sg += dot4(rA0, ld4(&part[320 + cq])) + dot4(rA1, ld4(&part[320 + cq + 4]))
            + dot4(rB0, ld4(&part[352 + cq])) + dot4(rB1, ld4(&part[352 + cq + 4]));
      }
      __syncthreads();
      if (dok) {
        float* hw = &h_s[dstT * 132 + 64 + cq];
        *(float4*)hw = rA0; *(float4*)(hw + 4) = rA1;
        *(float4*)(hw + 32) = rB0; *(float4*)(hw + 36) = rB1;
      }
      sp += __shfl_xor(sp, 1); sp += __shfl_xor(sp, 2);
      sg += __shfl_xor(sg, 1); sg += __shfl_xor(sg, 2);
      if (dok && (t & 3) == 0) { rawsc_s[dstT] = sp; hd[dstT] = sg; }
    }
    __syncthreads();

    // ========== P6: bitonic sort (raw dot desc, idx asc); LDS stages ping-pong
    float key = -INFINITY;
    int id = t & 255;
    if (t < n) key = rawsc_s[t];
    {
      int pp = 0;
      for (int size = 2; size <= 256; size <<= 1) {
        for (int stride = size >> 1; stride > 0; stride >>= 1) {
          if (stride > 32) {
            float* sb = pp ? (float*)part : sc;
            int* ib = pp ? ofs : idx;
            if (t < 256) { sb[t] = key; ib[t] = id; }
            __syncthreads();
            if (t < 256) {
              float pk = sb[t ^ stride];
              int pi = ib[t ^ stride];
              bool want = ((t & size) == 0);
              bool lowr = ((t & stride) == 0);
              bool mineFirst = (key > pk) || (key == pk && id < pi);
              if (mineFirst != (want == lowr)) { key = pk; id = pi; }
            }
            pp ^= 1;
          } else {
            if (t < 256) {
              float pk = __shfl_xor(key, stride);
              int pi = __shfl_xor(id, stride);
              bool want = ((t & size) == 0);
              bool lowr = ((t & stride) == 0);
              bool mineFirst = (key > pk) || (key == pk && id < pi);
              if (mineFirst != (want == lowr)) { key = pk; id = pi; }
            }
          }
        }
      }
    }
    __syncthreads();
    if (t < 256) idx[t] = id;
    __syncthreads();

    // ========== P7: tn, nmap, gates + per-wave max
    float gate = -INFINITY;
    if (t < k) {
      float tnv = tanhf(key / snorm_s);
      tn[t] = tnv;
      cnt[id] = t;
      gate = fmaf(hd[id], tnv, bgv);
    }
    if (wv < 4) {
      float m = gate;
#pragma unroll
      for (int o = 32; o > 0; o >>= 1) m = fmaxf(m, __shfl_xor(m, o));
      if (lane == 0) red[wv] = m;
    }
    __syncthreads();

    // ========== P8: softmax exp+sum (waves 0-3) || remap + next-layer histogram (waves 8-15)
    float ex = 0.f;
    if (wv < 4) {
      float m = fmaxf(fmaxf(red[0], red[1]), fmaxf(red[2], red[3]));
      ex = (t < k) ? __expf(gate - m) : 0.f;
      float s = ex;
#pragma unroll
      for (int o = 32; o > 0; o >>= 1) s += __shfl_xor(s, o);
      if (lane == 0) red[4 + wv] = s;
    } else if (wv >= 8 && layer < 2) {
      int tt = t - 512;
#pragma unroll
      for (int q = 0; q < 4; q++) {
        int e = tt + q * 512;
        unsigned u = es[e];
        unsigned o = DEADE;
        if (u != DEADE) {
          int ns = cnt[u & 0xFFFFu], nd = cnt[u >> 16];
          if (ns >= 0 && nd >= 0) o = (unsigned)ns | ((unsigned)nd << 16);
        }
        es[e] = o;
        if (o != DEADE) atomicAdd(&deg[o >> 16], 1);
      }
    }
    __syncthreads();

    // ========== P9: att weights
    if (t < 256) {
      float inv = 1.f / (red[4] + red[5] + red[6] + red[7]);
      float a = (t < k) ? ex * inv : 0.f;
      sc[t] = (layer == 2) ? a * tn[t] : a;
    }
    __syncthreads();

    if (layer < 2) {
      // ========== P10: in-LDS compaction, 2 passes x 2 column-groups
      {
        int rT = t >> 2;
        int cq4 = (t & 3) << 3;
        bool rok = rT < k;
        int src = 0; float tr = 0.f;
        if (rok) { src = idx[rT]; tr = tn[rT]; }
        float4 vA0, vA1, vB0, vB1;
        if (rok) {
          const float* hp = &h_s[src * 132 + cq4];
          vA0 = scale4(ld4(hp), tr);      vA1 = scale4(ld4(hp + 4), tr);
          vB0 = scale4(ld4(hp + 32), tr); vB1 = scale4(ld4(hp + 36), tr);
        }
        __syncthreads();
        if (rok) {
          float* hw = &h_s[rT * 132 + cq4];
          *(float4*)hw = vA0; *(float4*)(hw + 4) = vA1;
          *(float4*)(hw + 32) = vB0; *(float4*)(hw + 36) = vB1;
        }
        if (rok) {
          const float* hp = &h_s[src * 132 + 64 + cq4];
          vA0 = scale4(ld4(hp), tr);      vA1 = scale4(ld4(hp + 4), tr);
          vB0 = scale4(ld4(hp + 32), tr); vB1 = scale4(ld4(hp + 36), tr);
        }
        __syncthreads();
        if (rok) {
          float* hw = &h_s[rT * 132 + 64 + cq4];
          *(float4*)hw = vA0; *(float4*)(hw + 4) = vA1;
          *(float4*)(hw + 32) = vB0; *(float4*)(hw + 36) = vB1;
        }
      }
      __syncthreads();
      // ========== P11: attention partial sums over compacted rows
      if (t < 512) {
        int grp = t >> 7, c2 = t & 127;
        float pp2 = 0.f;
        for (int r = grp; r < k; r += 4) pp2 = fmaf(sc[r], h_s[r * 132 + c2], pp2);
        part[t] = pp2;
      }
      __syncthreads();
      if (t < 128) accout[t] += part[t] + part[128 + t] + part[256 + t] + part[384 + t];
      __syncthreads();
    } else {
      // ========== final attention (via idx, tn folded into sc) + output write
      if (t < 512) {
        int grp = t >> 7, c2 = t & 127;
        float pp2 = 0.f;
        for (int r = grp; r < k; r += 4) pp2 = fmaf(sc[r], h_s[idx[r] * 132 + c2], pp2);
        part[t] = pp2;
      }
      __syncthreads();
      if (t < 128)
        outp[(size_t)g * HDIM + t] =
            accout[t] + part[t] + part[128 + t] + part[256 + t] + part[384 + t];
    }
    n = k;
  }
}

// ================================================================ launch
extern "C" void kernel_launch(void* const* d_in, const int* in_sizes, int n_in,
                              void* d_out, int out_size, void* d_ws, size_t ws_size,
                              hipStream_t stream) {
  const float* x  = (const float*)d_in[0];
  const int*   ei = (const int*)d_in[1];
  const float* W0 = (const float*)d_in[2];
  const float* b0 = (const float*)d_in[3];
  const float* p0 = (const float*)d_in[4];
  const float* W1 = (const float*)d_in[5];
  const float* b1 = (const float*)d_in[6];
  const float* p1 = (const float*)d_in[7];
  const float* W2 = (const float*)d_in[8];
  const float* b2 = (const float*)d_in[9];
  const float* p2 = (const float*)d_in[10];
  const float* Wg = (const float*)d_in[11];
  const float* bg = (const float*)d_in[12];
  float* out = (float*)d_out;

  unsigned char* ws = (unsigned char*)d_ws;
  unsigned short* Wsp0 = (unsigned short*)(ws);
  unsigned short* Wsp1 = (unsigned short*)(ws + 98304ull);
  unsigned short* Wsp2 = (unsigned short*)(ws + 196608ull);

  k_wsplit<<<8, 256, 0, stream>>>(W0, Wsp0);
  k_wsplit<<<8, 256, 0, stream>>>(W1, Wsp1);
  k_wsplit<<<8, 256, 0, stream>>>(W2, Wsp2);
  k_net<<<GCOUNT, 1024, 0, stream>>>(x, ei, Wsp0, Wsp1, Wsp2,
                                     b0, p0, b1, p1, b2, p2, Wg, bg, out);
}